// Round 18
// baseline (192.337 us; speedup 1.0000x reference)
//
#include <hip/hip_runtime.h>

#define J_ 25
#define C_ 256
#define H_ 64
#define NPOS 8192
#define LOG2E 1.4426950408889634f
#define KSCALE 0.18033688011112042f   // 0.125 * LOG2E

typedef __attribute__((ext_vector_type(8))) short short8;   // 8 bf16
typedef __attribute__((ext_vector_type(4))) float f32x4;    // MFMA acc

__device__ __forceinline__ ushort f2b(float f) {
  union { float f; unsigned u; } v; v.f = f;
  unsigned r = v.u + 0x7FFFu + ((v.u >> 16) & 1u);  // RNE
  return (ushort)(r >> 16);
}
__device__ __forceinline__ float b2f(ushort u) {
  union { unsigned u; float f; } v; v.u = ((unsigned)u) << 16; return v.f;
}
// HW packed f32x2 -> bf16x2 (RNE), lo = a, hi = b
__device__ __forceinline__ uint cvtpk(float a, float b) {
  uint r;
  asm("v_cvt_pk_bf16_f32 %0, %1, %2" : "=v"(r) : "v"(a), "v"(b));
  return r;
}
// fully-streaming store: non-temporal, no-allocate at L1/L2/L3 (gfx950 flags)
__device__ __forceinline__ void stnt(float v, float* p) {
  asm volatile("global_store_dword %0, %1, off nt sc0 sc1"
               :: "v"(p), "v"(v) : "memory");
}

// ---------------------------------------------------------------------------
// Prepack: wpack = bf16 B-fragments of [Wq|Wk*KSCALE|Wv] (384 cols, 24 nt).
// bm2[j][a] = (att_bias[a] + bias_mat[j][a]) * LOG2E, -1e30 for a>=25.
// awT[j][h] = attn_w[h][j] * LOG2E.
// ---------------------------------------------------------------------------
__global__ void prepack_kernel(const float* __restrict__ Wq, const float* __restrict__ Wk,
                               const float* __restrict__ Wv, const float* __restrict__ bias_mat,
                               const float* __restrict__ att_bias, const float* __restrict__ attn_w,
                               ushort* __restrict__ wpack, float* __restrict__ bm2,
                               float* __restrict__ awT) {
  int idx = blockIdx.x * 256 + threadIdx.x;
  if (idx < 98304) {
    int e  = idx & 7;
    int l  = (idx >> 3) & 63;
    int ks = (idx >> 9) & 7;
    int nt = idx >> 12;                       // 0..23
    int k = ks * 32 + (l >> 4) * 8 + e;       // 0..255
    int n = nt * 16 + (l & 15);               // 0..383
    float v;
    if (n < H_)            v = Wq[k * H_ + n];
    else if (n < 2 * H_)   v = Wk[k * H_ + (n - H_)] * KSCALE;
    else                   v = Wv[k * C_ + (n - 2 * H_)];
    wpack[idx] = f2b(v);
  } else if (idx < 98304 + 1024) {
    int j2 = idx - 98304;
    int j = j2 >> 5, a = j2 & 31;
    float v;
    if (a < J_) v = (att_bias[a] + ((j < J_) ? bias_mat[j * J_ + a] : 0.f)) * LOG2E;
    else        v = -1e30f;
    bm2[j2] = v;
  } else if (idx < 98304 + 1024 + 1600) {
    int j2 = idx - (98304 + 1024);
    int j = j2 >> 6, h = j2 & 63;             // j<25, h<64
    awT[j2] = attn_w[h * J_ + j] * LOG2E;
  }
}

// ---------------------------------------------------------------------------
// Fused kernel: SPATIAL 2-position blocks (R15/R17 structure, verbatim) with
// fully-streaming final stores (nt sc0 sc1) — the out stream must not
// allocate in L2 OR the 256 MB Infinity Cache, so x (209 MB) stays
// L3-resident across graph replays and phase-0 staging hits L3.
// ---------------------------------------------------------------------------
__global__ __launch_bounds__(512) void fused_attn_kernel(
    const float* __restrict__ x,
    const float* __restrict__ bq, const float* __restrict__ bk,
    const float* __restrict__ bv,
    const float* __restrict__ ln_g, const float* __restrict__ ln_b,
    const ushort* __restrict__ wpack, const float* __restrict__ bm2,
    const float* __restrict__ awT,
    float* __restrict__ out)
{
  __shared__ __align__(16) char SMEM[2 * 25088];

  const int t   = threadIdx.x;
  const int ph  = t >> 8;                     // position half 0/1
  const int tt  = t & 255;                    // thread within position
  char* BASE = SMEM + ph * 25088;
  ushort* VT = (ushort*)BASE;                 // [256][32] bf16 (phase 3)
  ushort* XS = (ushort*)BASE;                 // [25][256] bf16 (phases 0-1, aliases VT)
  ushort* QS = (ushort*)(BASE + 16384);       // [32][64]  4096 B
  ushort* KS = (ushort*)(BASE + 20480);       // [32][64]  4096 B
  float*  ST = (float*)(BASE + 24576);        // [32][4]   512 B

  const int lane = tt & 63;
  const int w    = tt >> 6;
  const int l15  = lane & 15;
  const int lhi  = lane >> 4;
  const int half = w & 1;
  const int mtw  = w >> 1;
  const int pos  = blockIdx.x * 2 + ph;

  const int hcol = w * 16 + l15;                  // 0..63
  const float* xg = x + (size_t)pos * 6400;
  const ushort* wbase = wpack + w * 4096 + (size_t)lane * 8;

  float biasv[6];
  // ---- phase 0: stage x -> XS bf16 (coalesced) + small prefetches ----
  {
    float4 xf[7];
#pragma unroll
    for (int i = 0; i < 6; ++i)
      xf[i] = *reinterpret_cast<const float4*>(xg + (i * 256 + tt) * 4);
    if (tt < 64) xf[6] = *reinterpret_cast<const float4*>(xg + (1536 + tt) * 4);

    biasv[0] = bq[hcol];
    biasv[1] = bk[hcol] * KSCALE;
    biasv[2] = bv[hcol];
    biasv[3] = bv[64 + hcol];
    biasv[4] = bv[128 + hcol];
    biasv[5] = bv[192 + hcol];

#pragma unroll
    for (int i = 0; i < 7; ++i) {
      if (i < 6 || tt < 64) {
        int f = i * 256 + tt;
        int row = f >> 6;                     // 0..24
        int c = (f & 63) * 4;
        int ci = c ^ ((row & 7) << 3);
        uint2 pk;
        pk.x = cvtpk(xf[i].x, xf[i].y);
        pk.y = cvtpk(xf[i].z, xf[i].w);
        *reinterpret_cast<uint2*>(&XS[row * 256 + ci]) = pk;
      }
    }
  }
  // prefetch ks=0 weight fragments (independent of XS)
  short8 bf0[6];
#pragma unroll
  for (int i = 0; i < 6; ++i)
    bf0[i] = *reinterpret_cast<const short8*>(wbase + i * 16384);
  __syncthreads();   // bar1: XS ready (both halves)

  // ---- phase 1: projections (ks-outer)  [32x256] @ [256x384] ----
  f32x4 acc[2][6];
  uint resb[16];     // packed bf16 residual (row pairs)
  {
#pragma unroll
    for (int m = 0; m < 2; ++m)
#pragma unroll
      for (int i = 0; i < 6; ++i) acc[m][i] = (f32x4){0.f, 0.f, 0.f, 0.f};

    const int row1 = (l15 < 9) ? 16 + l15 : 0;  // clamped pad row (garbage ok)
    __builtin_amdgcn_s_setprio(1);
#pragma unroll
    for (int ks = 0; ks < 8; ++ks) {
      int co = ks * 32 + lhi * 8;
      short8 a0 = *reinterpret_cast<const short8*>(&XS[l15 * 256 + (co ^ ((l15 & 7) << 3))]);
      short8 a1 = *reinterpret_cast<const short8*>(&XS[row1 * 256 + (co ^ ((row1 & 7) << 3))]);
#pragma unroll
      for (int i = 0; i < 6; ++i) {
        short8 bfr;
        if (ks == 0) bfr = bf0[i];
        else         bfr = *reinterpret_cast<const short8*>(wbase + i * 16384 + ks * 512);
        acc[0][i] = __builtin_amdgcn_mfma_f32_16x16x32_bf16(a0, bfr, acc[0][i], 0, 0, 0);
        acc[1][i] = __builtin_amdgcn_mfma_f32_16x16x32_bf16(a1, bfr, acc[1][i], 0, 0, 0);
      }
    }
    __builtin_amdgcn_s_setprio(0);

    // awT fold values (L2-hot; already *LOG2E)
    float awv[8];
#pragma unroll
    for (int m = 0; m < 2; ++m)
#pragma unroll
      for (int r = 0; r < 4; ++r) {
        int row = m * 16 + lhi * 4 + r;
        int ac = row < J_ ? row : J_ - 1;
        awv[m * 4 + r] = awT[ac * 64 + hcol];
      }

    // epilogue A: QS and KS (non-aliased region); cvt_pk pairs + hi-extract
#pragma unroll
    for (int m = 0; m < 2; ++m) {
      float q0 = acc[m][0][0] + biasv[0], q1 = acc[m][0][1] + biasv[0];
      float q2 = acc[m][0][2] + biasv[0], q3 = acc[m][0][3] + biasv[0];
      float k0 = acc[m][1][0] + biasv[1] + awv[m * 4 + 0];
      float k1 = acc[m][1][1] + biasv[1] + awv[m * 4 + 1];
      float k2 = acc[m][1][2] + biasv[1] + awv[m * 4 + 2];
      float k3 = acc[m][1][3] + biasv[1] + awv[m * 4 + 3];
      uint qp0 = cvtpk(q0, q1), qp1 = cvtpk(q2, q3);
      uint kp0 = cvtpk(k0, k1), kp1 = cvtpk(k2, k3);
#pragma unroll
      for (int r = 0; r < 4; ++r) {
        int row = m * 16 + lhi * 4 + r;
        int sw  = (row & 7) << 3;
        uint qp = (r < 2) ? qp0 : qp1;
        uint kp = (r < 2) ? kp0 : kp1;
        ushort qv = (r & 1) ? (ushort)(qp >> 16) : (ushort)(qp & 0xffff);
        ushort kv = (r & 1) ? (ushort)(kp >> 16) : (ushort)(kp & 0xffff);
        QS[row * 64 + (hcol ^ sw)] = qv;
        KS[row * 64 + (hcol ^ sw)] = kv;
      }
    }

    // residual extraction from XS (must finish before bar2; packed bf16)
#pragma unroll
    for (int i = 0; i < 8; ++i) {
      int c = (half * 8 + i) * 16 + l15;
#pragma unroll
      for (int rr = 0; rr < 2; ++rr) {
        int row0 = mtw * 16 + lhi * 4 + 2 * rr;
        int rc0 = row0 < J_ ? row0 : J_ - 1;
        int rc1 = (row0 + 1) < J_ ? row0 + 1 : J_ - 1;
        ushort u0 = XS[rc0 * 256 + (c ^ ((rc0 & 7) << 3))];
        ushort u1 = XS[rc1 * 256 + (c ^ ((rc1 & 7) << 3))];
        resb[i * 2 + rr] = (uint)u0 | ((uint)u1 << 16);
      }
    }
  }
  __syncthreads();   // bar2: all XS reads retired; QS/KS visible

  // epilogue B: V^T into VT (overlays XS) — batched 4-row uint2 writes
  {
#pragma unroll
    for (int i = 2; i < 6; ++i) {
      int c = hcol + (i - 2) * 64;
      int csw = (c & 3) << 3;
#pragma unroll
      for (int m = 0; m < 2; ++m) {
        int row0 = m * 16 + lhi * 4;
        uint2 pk;
        pk.x = cvtpk(acc[m][i][0] + biasv[i], acc[m][i][1] + biasv[i]);
        pk.y = cvtpk(acc[m][i][2] + biasv[i], acc[m][i][3] + biasv[i]);
        *reinterpret_cast<uint2*>(&VT[c * 32 + (row0 ^ csw)]) = pk;
      }
    }
  }
  __syncthreads();   // bar3: VT visible; softmax+PV run barrier-free

  // ---- phase 2: scores (transposed) + wave-parallel softmax + shuffle-P ----
  short8 pa;
  {
    const int jrow = mtw * 16 + l15;
    const int jsw  = (jrow & 7) << 3;
    short8 qf0 = *reinterpret_cast<const short8*>(&QS[jrow * 64 + ((lhi * 8) ^ jsw)]);
    short8 qf1 = *reinterpret_cast<const short8*>(&QS[jrow * 64 + ((32 + lhi * 8) ^ jsw)]);

    const int a0r = l15, a1r = 16 + l15;
    const int s0w = (a0r & 7) << 3, s1w = (a1r & 7) << 3;
    short8 m00 = *reinterpret_cast<const short8*>(&KS[a0r * 64 + ((lhi * 8) ^ s0w)]);
    short8 m01 = *reinterpret_cast<const short8*>(&KS[a0r * 64 + ((32 + lhi * 8) ^ s0w)]);
    short8 m10 = *reinterpret_cast<const short8*>(&KS[a1r * 64 + ((lhi * 8) ^ s1w)]);
    short8 m11 = *reinterpret_cast<const short8*>(&KS[a1r * 64 + ((32 + lhi * 8) ^ s1w)]);

    f32x4 s0 = {0.f, 0.f, 0.f, 0.f}, s1 = {0.f, 0.f, 0.f, 0.f};
    __builtin_amdgcn_s_setprio(1);
    s0 = __builtin_amdgcn_mfma_f32_16x16x32_bf16(m00, qf0, s0, 0, 0, 0);
    s0 = __builtin_amdgcn_mfma_f32_16x16x32_bf16(m01, qf1, s0, 0, 0, 0);
    s1 = __builtin_amdgcn_mfma_f32_16x16x32_bf16(m10, qf0, s1, 0, 0, 0);
    s1 = __builtin_amdgcn_mfma_f32_16x16x32_bf16(m11, qf1, s1, 0, 0, 0);
    __builtin_amdgcn_s_setprio(0);

    float4 bm0 = *reinterpret_cast<const float4*>(&bm2[jrow * 32 + lhi * 4]);
    float4 bm1 = *reinterpret_cast<const float4*>(&bm2[jrow * 32 + 16 + lhi * 4]);
    float v0[4], v1[4];
    v0[0] = s0[0] + bm0.x; v0[1] = s0[1] + bm0.y; v0[2] = s0[2] + bm0.z; v0[3] = s0[3] + bm0.w;
    v1[0] = s1[0] + bm1.x; v1[1] = s1[1] + bm1.y; v1[2] = s1[2] + bm1.z; v1[3] = s1[3] + bm1.w;

    float mx = fmaxf(fmaxf(fmaxf(v0[0], v0[1]), fmaxf(v0[2], v0[3])),
                     fmaxf(fmaxf(v1[0], v1[1]), fmaxf(v1[2], v1[3])));
    mx = fmaxf(mx, __shfl_xor(mx, 16));
    mx = fmaxf(mx, __shfl_xor(mx, 32));

    float e0[4], e1[4], sum = 0.f;
#pragma unroll
    for (int r = 0; r < 4; ++r) { e0[r] = __builtin_exp2f(v0[r] - mx); sum += e0[r]; }
#pragma unroll
    for (int r = 0; r < 4; ++r) { e1[r] = __builtin_exp2f(v1[r] - mx); sum += e1[r]; }
    sum += __shfl_xor(sum, 16);
    sum += __shfl_xor(sum, 32);
    float inv = 1.0f / sum;

    uint w0 = cvtpk(e0[0] * inv, e0[1] * inv);
    uint w1 = cvtpk(e0[2] * inv, e0[3] * inv);
    uint w2 = cvtpk(e1[0] * inv, e1[1] * inv);
    uint w3 = cvtpk(e1[2] * inv, e1[3] * inv);

    // consumer lane (l15,lhi) wants P[jrow][k = lhi*8 .. lhi*8+7]
    int srcA = l15 + (((lhi * 2) & 3) << 4);
    int srcB = srcA + 16;
    uint a0s = (uint)__shfl((int)w0, srcA);
    uint a1s = (uint)__shfl((int)w1, srcA);
    uint a2s = (uint)__shfl((int)w0, srcB);
    uint a3s = (uint)__shfl((int)w1, srcB);
    uint b0s = (uint)__shfl((int)w2, srcA);
    uint b1s = (uint)__shfl((int)w3, srcA);
    uint b2s = (uint)__shfl((int)w2, srcB);
    uint b3s = (uint)__shfl((int)w3, srcB);
    bool sel = lhi >= 2;
    union { uint u[4]; short8 s; } pau;
    pau.u[0] = sel ? b0s : a0s;
    pau.u[1] = sel ? b1s : a1s;
    pau.u[2] = sel ? b2s : a2s;
    pau.u[3] = sel ? b3s : a3s;
    pa = pau.s;
  }

  // ---- phase 3: PV + packed-register residual + LN stats ----
  float y[8][4];
  {
    float s1a[4] = {0.f, 0.f, 0.f, 0.f}, s2a[4] = {0.f, 0.f, 0.f, 0.f};
    __builtin_amdgcn_s_setprio(1);
#pragma unroll
    for (int i = 0; i < 8; ++i) {
      int c = (half * 8 + i) * 16 + l15;
      short8 vb = *reinterpret_cast<const short8*>(
          &VT[c * 32 + ((lhi * 8) ^ ((c & 3) << 3))]);
      f32x4 z = {0.f, 0.f, 0.f, 0.f};
      f32x4 av = __builtin_amdgcn_mfma_f32_16x16x32_bf16(pa, vb, z, 0, 0, 0);
#pragma unroll
      for (int r = 0; r < 4; ++r) {
        uint pr = resb[i * 2 + (r >> 1)];
        ushort ub = (r & 1) ? (ushort)(pr >> 16) : (ushort)(pr & 0xffff);
        float yy = av[r] + b2f(ub);
        y[i][r] = yy;
        s1a[r] += yy;
        s2a[r] += yy * yy;
      }
    }
    __builtin_amdgcn_s_setprio(0);
#pragma unroll
    for (int d = 1; d < 16; d <<= 1) {
#pragma unroll
      for (int r = 0; r < 4; ++r) {
        s1a[r] += __shfl_xor(s1a[r], d);
        s2a[r] += __shfl_xor(s2a[r], d);
      }
    }
    if (l15 == 0) {
#pragma unroll
      for (int r = 0; r < 4; ++r) {
        int row = mtw * 16 + lhi * 4 + r;
        float2 st; st.x = s1a[r]; st.y = s2a[r];
        *reinterpret_cast<float2*>(&ST[row * 4 + half * 2]) = st;
      }
    }
  }
  __syncthreads();   // bar4: ST ready

  // ---- phase 4: LayerNorm + fully-streaming store (nt sc0 sc1) ----
  {
    float* ob = out + (size_t)pos * 6400;
    float mu[4], rstd[4];
    bool wr[4];
#pragma unroll
    for (int r = 0; r < 4; ++r) {
      int row = mtw * 16 + lhi * 4 + r;
      float4 st = *reinterpret_cast<const float4*>(&ST[row * 4]);
      float ssum = st.x + st.z;
      float ssq  = st.y + st.w;
      float m = ssum * (1.f / 256.f);
      float var = ssq * (1.f / 256.f) - m * m;
      mu[r] = m;
      rstd[r] = rsqrtf(var + 1e-5f);
      wr[r] = row < J_;
    }
#pragma unroll
    for (int i = 0; i < 8; ++i) {
      int c = half * 128 + i * 16 + l15;
      float g = ln_g[c];
      float b = ln_b[c];
#pragma unroll
      for (int r = 0; r < 4; ++r) {
        if (wr[r]) {
          int row = mtw * 16 + lhi * 4 + r;
          stnt((y[i][r] - mu[r]) * rstd[r] * g + b, &ob[row * 256 + c]);
        }
      }
    }
  }
}

// ---------------------------------------------------------------------------
extern "C" void kernel_launch(void* const* d_in, const int* in_sizes, int n_in,
                              void* d_out, int out_size, void* d_ws, size_t ws_size,
                              hipStream_t stream) {
  const float* x        = (const float*)d_in[0];
  const float* bias_mat = (const float*)d_in[1];
  const float* Wq       = (const float*)d_in[2];
  const float* bq       = (const float*)d_in[3];
  const float* Wk       = (const float*)d_in[4];
  const float* bk       = (const float*)d_in[5];
  const float* Wv       = (const float*)d_in[6];
  const float* bv       = (const float*)d_in[7];
  const float* attn_w   = (const float*)d_in[8];
  const float* att_bias = (const float*)d_in[9];
  const float* ln_g     = (const float*)d_in[10];
  const float* ln_b     = (const float*)d_in[11];
  float* out = (float*)d_out;

  ushort* wpack = (ushort*)d_ws;                       // 196608 B
  float*  bm2   = (float*)((char*)d_ws + 196608);      // 4096 B
  float*  awT   = (float*)((char*)d_ws + 200704);      // 6400 B

  prepack_kernel<<<395, 256, 0, stream>>>(Wq, Wk, Wv, bias_mat, att_bias, attn_w,
                                          wpack, bm2, awT);
  fused_attn_kernel<<<NPOS / 2, 512, 0, stream>>>(x, bq, bk, bv, ln_g, ln_b,
                                                  wpack, bm2, awT, out);
}

// Round 20
// 157.527 us; speedup vs baseline: 1.2210x; 1.2210x over previous
//
#include <hip/hip_runtime.h>

#define J_ 25
#define C_ 256
#define H_ 64
#define NPOS 8192
#define LOG2E 1.4426950408889634f
#define KSCALE 0.18033688011112042f   // 0.125 * LOG2E

typedef __attribute__((ext_vector_type(8))) short short8;   // 8 bf16
typedef __attribute__((ext_vector_type(4))) float f32x4;    // MFMA acc / native float4

__device__ __forceinline__ ushort f2b(float f) {
  union { float f; unsigned u; } v; v.f = f;
  unsigned r = v.u + 0x7FFFu + ((v.u >> 16) & 1u);  // RNE
  return (ushort)(r >> 16);
}
__device__ __forceinline__ float b2f(ushort u) {
  union { unsigned u; float f; } v; v.u = ((unsigned)u) << 16; return v.f;
}
// HW packed f32x2 -> bf16x2 (RNE), lo = a, hi = b
__device__ __forceinline__ uint cvtpk(float a, float b) {
  uint r;
  asm("v_cvt_pk_bf16_f32 %0, %1, %2" : "=v"(r) : "v"(a), "v"(b));
  return r;
}

// ---------------------------------------------------------------------------
// Prepack: wpack = bf16 B-fragments of [Wq|Wk*KSCALE|Wv] (384 cols, 24 nt).
// bm2[j][a] = (att_bias[a] + bias_mat[j][a]) * LOG2E, -1e30 for a>=25.
// awT[j][h] = attn_w[h][j] * LOG2E.
// ---------------------------------------------------------------------------
__global__ void prepack_kernel(const float* __restrict__ Wq, const float* __restrict__ Wk,
                               const float* __restrict__ Wv, const float* __restrict__ bias_mat,
                               const float* __restrict__ att_bias, const float* __restrict__ attn_w,
                               ushort* __restrict__ wpack, float* __restrict__ bm2,
                               float* __restrict__ awT) {
  int idx = blockIdx.x * 256 + threadIdx.x;
  if (idx < 98304) {
    int e  = idx & 7;
    int l  = (idx >> 3) & 63;
    int ks = (idx >> 9) & 7;
    int nt = idx >> 12;                       // 0..23
    int k = ks * 32 + (l >> 4) * 8 + e;       // 0..255
    int n = nt * 16 + (l & 15);               // 0..383
    float v;
    if (n < H_)            v = Wq[k * H_ + n];
    else if (n < 2 * H_)   v = Wk[k * H_ + (n - H_)] * KSCALE;
    else                   v = Wv[k * C_ + (n - 2 * H_)];
    wpack[idx] = f2b(v);
  } else if (idx < 98304 + 1024) {
    int j2 = idx - 98304;
    int j = j2 >> 5, a = j2 & 31;
    float v;
    if (a < J_) v = (att_bias[a] + ((j < J_) ? bias_mat[j * J_ + a] : 0.f)) * LOG2E;
    else        v = -1e30f;
    bm2[j2] = v;
  } else if (idx < 98304 + 1024 + 1600) {
    int j2 = idx - (98304 + 1024);
    int j = j2 >> 6, h = j2 & 63;             // j<25, h<64
    awT[j2] = attn_w[h * J_ + j] * LOG2E;
  }
}

// ---------------------------------------------------------------------------
// Fused kernel: SPATIAL 2-position blocks (R17 structure) with nontemporal
// stores made FULLY COALESCED: phase 4a normalizes into bf16 in the dead VT
// region; phase 4b streams it out as lane-contiguous f32x4 nt stores
// (1 KB/instr, full-line write combining — removes R17's 58 MB partial-line
// write overhead while keeping the L2-bypass win).
// ---------------------------------------------------------------------------
__global__ __launch_bounds__(512) void fused_attn_kernel(
    const float* __restrict__ x,
    const float* __restrict__ bq, const float* __restrict__ bk,
    const float* __restrict__ bv,
    const float* __restrict__ ln_g, const float* __restrict__ ln_b,
    const ushort* __restrict__ wpack, const float* __restrict__ bm2,
    const float* __restrict__ awT,
    float* __restrict__ out)
{
  __shared__ __align__(16) char SMEM[2 * 25088];

  const int t   = threadIdx.x;
  const int ph  = t >> 8;                     // position half 0/1
  const int tt  = t & 255;                    // thread within position
  char* BASE = SMEM + ph * 25088;
  ushort* VT = (ushort*)BASE;                 // [256][32] bf16 (phase 3) / y-out (4a)
  ushort* XS = (ushort*)BASE;                 // [25][256] bf16 (phases 0-1, aliases VT)
  ushort* QS = (ushort*)(BASE + 16384);       // [32][64]  4096 B
  ushort* KS = (ushort*)(BASE + 20480);       // [32][64]  4096 B
  float*  ST = (float*)(BASE + 24576);        // [32][4]   512 B

  const int lane = tt & 63;
  const int w    = tt >> 6;
  const int l15  = lane & 15;
  const int lhi  = lane >> 4;
  const int half = w & 1;
  const int mtw  = w >> 1;
  const int pos  = blockIdx.x * 2 + ph;

  const int hcol = w * 16 + l15;                  // 0..63
  const float* xg = x + (size_t)pos * 6400;
  const ushort* wbase = wpack + w * 4096 + (size_t)lane * 8;

  float biasv[6];
  // ---- phase 0: stage x -> XS bf16 (coalesced) + small prefetches ----
  {
    float4 xf[7];
#pragma unroll
    for (int i = 0; i < 6; ++i)
      xf[i] = *reinterpret_cast<const float4*>(xg + (i * 256 + tt) * 4);
    if (tt < 64) xf[6] = *reinterpret_cast<const float4*>(xg + (1536 + tt) * 4);

    biasv[0] = bq[hcol];
    biasv[1] = bk[hcol] * KSCALE;
    biasv[2] = bv[hcol];
    biasv[3] = bv[64 + hcol];
    biasv[4] = bv[128 + hcol];
    biasv[5] = bv[192 + hcol];

#pragma unroll
    for (int i = 0; i < 7; ++i) {
      if (i < 6 || tt < 64) {
        int f = i * 256 + tt;
        int row = f >> 6;                     // 0..24
        int c = (f & 63) * 4;
        int ci = c ^ ((row & 7) << 3);
        uint2 pk;
        pk.x = cvtpk(xf[i].x, xf[i].y);
        pk.y = cvtpk(xf[i].z, xf[i].w);
        *reinterpret_cast<uint2*>(&XS[row * 256 + ci]) = pk;
      }
    }
  }
  // prefetch ks=0 weight fragments (independent of XS)
  short8 bf0[6];
#pragma unroll
  for (int i = 0; i < 6; ++i)
    bf0[i] = *reinterpret_cast<const short8*>(wbase + i * 16384);
  __syncthreads();   // bar1: XS ready (both halves)

  // ---- phase 1: projections (ks-outer)  [32x256] @ [256x384] ----
  f32x4 acc[2][6];
  uint resb[16];     // packed bf16 residual (row pairs)
  {
#pragma unroll
    for (int m = 0; m < 2; ++m)
#pragma unroll
      for (int i = 0; i < 6; ++i) acc[m][i] = (f32x4){0.f, 0.f, 0.f, 0.f};

    const int row1 = (l15 < 9) ? 16 + l15 : 0;  // clamped pad row (garbage ok)
    __builtin_amdgcn_s_setprio(1);
#pragma unroll
    for (int ks = 0; ks < 8; ++ks) {
      int co = ks * 32 + lhi * 8;
      short8 a0 = *reinterpret_cast<const short8*>(&XS[l15 * 256 + (co ^ ((l15 & 7) << 3))]);
      short8 a1 = *reinterpret_cast<const short8*>(&XS[row1 * 256 + (co ^ ((row1 & 7) << 3))]);
#pragma unroll
      for (int i = 0; i < 6; ++i) {
        short8 bfr;
        if (ks == 0) bfr = bf0[i];
        else         bfr = *reinterpret_cast<const short8*>(wbase + i * 16384 + ks * 512);
        acc[0][i] = __builtin_amdgcn_mfma_f32_16x16x32_bf16(a0, bfr, acc[0][i], 0, 0, 0);
        acc[1][i] = __builtin_amdgcn_mfma_f32_16x16x32_bf16(a1, bfr, acc[1][i], 0, 0, 0);
      }
    }
    __builtin_amdgcn_s_setprio(0);

    // awT fold values (L2-hot; already *LOG2E)
    float awv[8];
#pragma unroll
    for (int m = 0; m < 2; ++m)
#pragma unroll
      for (int r = 0; r < 4; ++r) {
        int row = m * 16 + lhi * 4 + r;
        int ac = row < J_ ? row : J_ - 1;
        awv[m * 4 + r] = awT[ac * 64 + hcol];
      }

    // epilogue A: QS and KS (non-aliased region); cvt_pk pairs + hi-extract
#pragma unroll
    for (int m = 0; m < 2; ++m) {
      float q0 = acc[m][0][0] + biasv[0], q1 = acc[m][0][1] + biasv[0];
      float q2 = acc[m][0][2] + biasv[0], q3 = acc[m][0][3] + biasv[0];
      float k0 = acc[m][1][0] + biasv[1] + awv[m * 4 + 0];
      float k1 = acc[m][1][1] + biasv[1] + awv[m * 4 + 1];
      float k2 = acc[m][1][2] + biasv[1] + awv[m * 4 + 2];
      float k3 = acc[m][1][3] + biasv[1] + awv[m * 4 + 3];
      uint qp0 = cvtpk(q0, q1), qp1 = cvtpk(q2, q3);
      uint kp0 = cvtpk(k0, k1), kp1 = cvtpk(k2, k3);
#pragma unroll
      for (int r = 0; r < 4; ++r) {
        int row = m * 16 + lhi * 4 + r;
        int sw  = (row & 7) << 3;
        uint qp = (r < 2) ? qp0 : qp1;
        uint kp = (r < 2) ? kp0 : kp1;
        ushort qv = (r & 1) ? (ushort)(qp >> 16) : (ushort)(qp & 0xffff);
        ushort kv = (r & 1) ? (ushort)(kp >> 16) : (ushort)(kp & 0xffff);
        QS[row * 64 + (hcol ^ sw)] = qv;
        KS[row * 64 + (hcol ^ sw)] = kv;
      }
    }

    // residual extraction from XS (must finish before bar2; packed bf16)
#pragma unroll
    for (int i = 0; i < 8; ++i) {
      int c = (half * 8 + i) * 16 + l15;
#pragma unroll
      for (int rr = 0; rr < 2; ++rr) {
        int row0 = mtw * 16 + lhi * 4 + 2 * rr;
        int rc0 = row0 < J_ ? row0 : J_ - 1;
        int rc1 = (row0 + 1) < J_ ? row0 + 1 : J_ - 1;
        ushort u0 = XS[rc0 * 256 + (c ^ ((rc0 & 7) << 3))];
        ushort u1 = XS[rc1 * 256 + (c ^ ((rc1 & 7) << 3))];
        resb[i * 2 + rr] = (uint)u0 | ((uint)u1 << 16);
      }
    }
  }
  __syncthreads();   // bar2: all XS reads retired; QS/KS visible

  // epilogue B: V^T into VT (overlays XS) — batched 4-row uint2 writes
  {
#pragma unroll
    for (int i = 2; i < 6; ++i) {
      int c = hcol + (i - 2) * 64;
      int csw = (c & 3) << 3;
#pragma unroll
      for (int m = 0; m < 2; ++m) {
        int row0 = m * 16 + lhi * 4;
        uint2 pk;
        pk.x = cvtpk(acc[m][i][0] + biasv[i], acc[m][i][1] + biasv[i]);
        pk.y = cvtpk(acc[m][i][2] + biasv[i], acc[m][i][3] + biasv[i]);
        *reinterpret_cast<uint2*>(&VT[c * 32 + (row0 ^ csw)]) = pk;
      }
    }
  }
  __syncthreads();   // bar3: VT visible; softmax+PV run barrier-free

  // ---- phase 2: scores (transposed) + wave-parallel softmax + shuffle-P ----
  short8 pa;
  {
    const int jrow = mtw * 16 + l15;
    const int jsw  = (jrow & 7) << 3;
    short8 qf0 = *reinterpret_cast<const short8*>(&QS[jrow * 64 + ((lhi * 8) ^ jsw)]);
    short8 qf1 = *reinterpret_cast<const short8*>(&QS[jrow * 64 + ((32 + lhi * 8) ^ jsw)]);

    const int a0r = l15, a1r = 16 + l15;
    const int s0w = (a0r & 7) << 3, s1w = (a1r & 7) << 3;
    short8 m00 = *reinterpret_cast<const short8*>(&KS[a0r * 64 + ((lhi * 8) ^ s0w)]);
    short8 m01 = *reinterpret_cast<const short8*>(&KS[a0r * 64 + ((32 + lhi * 8) ^ s0w)]);
    short8 m10 = *reinterpret_cast<const short8*>(&KS[a1r * 64 + ((lhi * 8) ^ s1w)]);
    short8 m11 = *reinterpret_cast<const short8*>(&KS[a1r * 64 + ((32 + lhi * 8) ^ s1w)]);

    f32x4 s0 = {0.f, 0.f, 0.f, 0.f}, s1 = {0.f, 0.f, 0.f, 0.f};
    __builtin_amdgcn_s_setprio(1);
    s0 = __builtin_amdgcn_mfma_f32_16x16x32_bf16(m00, qf0, s0, 0, 0, 0);
    s0 = __builtin_amdgcn_mfma_f32_16x16x32_bf16(m01, qf1, s0, 0, 0, 0);
    s1 = __builtin_amdgcn_mfma_f32_16x16x32_bf16(m10, qf0, s1, 0, 0, 0);
    s1 = __builtin_amdgcn_mfma_f32_16x16x32_bf16(m11, qf1, s1, 0, 0, 0);
    __builtin_amdgcn_s_setprio(0);

    float4 bm0 = *reinterpret_cast<const float4*>(&bm2[jrow * 32 + lhi * 4]);
    float4 bm1 = *reinterpret_cast<const float4*>(&bm2[jrow * 32 + 16 + lhi * 4]);
    float v0[4], v1[4];
    v0[0] = s0[0] + bm0.x; v0[1] = s0[1] + bm0.y; v0[2] = s0[2] + bm0.z; v0[3] = s0[3] + bm0.w;
    v1[0] = s1[0] + bm1.x; v1[1] = s1[1] + bm1.y; v1[2] = s1[2] + bm1.z; v1[3] = s1[3] + bm1.w;

    float mx = fmaxf(fmaxf(fmaxf(v0[0], v0[1]), fmaxf(v0[2], v0[3])),
                     fmaxf(fmaxf(v1[0], v1[1]), fmaxf(v1[2], v1[3])));
    mx = fmaxf(mx, __shfl_xor(mx, 16));
    mx = fmaxf(mx, __shfl_xor(mx, 32));

    float e0[4], e1[4], sum = 0.f;
#pragma unroll
    for (int r = 0; r < 4; ++r) { e0[r] = __builtin_exp2f(v0[r] - mx); sum += e0[r]; }
#pragma unroll
    for (int r = 0; r < 4; ++r) { e1[r] = __builtin_exp2f(v1[r] - mx); sum += e1[r]; }
    sum += __shfl_xor(sum, 16);
    sum += __shfl_xor(sum, 32);
    float inv = 1.0f / sum;

    uint w0 = cvtpk(e0[0] * inv, e0[1] * inv);
    uint w1 = cvtpk(e0[2] * inv, e0[3] * inv);
    uint w2 = cvtpk(e1[0] * inv, e1[1] * inv);
    uint w3 = cvtpk(e1[2] * inv, e1[3] * inv);

    // consumer lane (l15,lhi) wants P[jrow][k = lhi*8 .. lhi*8+7]
    int srcA = l15 + (((lhi * 2) & 3) << 4);
    int srcB = srcA + 16;
    uint a0s = (uint)__shfl((int)w0, srcA);
    uint a1s = (uint)__shfl((int)w1, srcA);
    uint a2s = (uint)__shfl((int)w0, srcB);
    uint a3s = (uint)__shfl((int)w1, srcB);
    uint b0s = (uint)__shfl((int)w2, srcA);
    uint b1s = (uint)__shfl((int)w3, srcA);
    uint b2s = (uint)__shfl((int)w2, srcB);
    uint b3s = (uint)__shfl((int)w3, srcB);
    bool sel = lhi >= 2;
    union { uint u[4]; short8 s; } pau;
    pau.u[0] = sel ? b0s : a0s;
    pau.u[1] = sel ? b1s : a1s;
    pau.u[2] = sel ? b2s : a2s;
    pau.u[3] = sel ? b3s : a3s;
    pa = pau.s;
  }

  // ---- phase 3: PV + packed-register residual + LN stats ----
  float y[8][4];
  {
    float s1a[4] = {0.f, 0.f, 0.f, 0.f}, s2a[4] = {0.f, 0.f, 0.f, 0.f};
    __builtin_amdgcn_s_setprio(1);
#pragma unroll
    for (int i = 0; i < 8; ++i) {
      int c = (half * 8 + i) * 16 + l15;
      short8 vb = *reinterpret_cast<const short8*>(
          &VT[c * 32 + ((lhi * 8) ^ ((c & 3) << 3))]);
      f32x4 z = {0.f, 0.f, 0.f, 0.f};
      f32x4 av = __builtin_amdgcn_mfma_f32_16x16x32_bf16(pa, vb, z, 0, 0, 0);
#pragma unroll
      for (int r = 0; r < 4; ++r) {
        uint pr = resb[i * 2 + (r >> 1)];
        ushort ub = (r & 1) ? (ushort)(pr >> 16) : (ushort)(pr & 0xffff);
        float yy = av[r] + b2f(ub);
        y[i][r] = yy;
        s1a[r] += yy;
        s2a[r] += yy * yy;
      }
    }
    __builtin_amdgcn_s_setprio(0);
#pragma unroll
    for (int d = 1; d < 16; d <<= 1) {
#pragma unroll
      for (int r = 0; r < 4; ++r) {
        s1a[r] += __shfl_xor(s1a[r], d);
        s2a[r] += __shfl_xor(s2a[r], d);
      }
    }
    if (l15 == 0) {
#pragma unroll
      for (int r = 0; r < 4; ++r) {
        int row = mtw * 16 + lhi * 4 + r;
        float2 st; st.x = s1a[r]; st.y = s2a[r];
        *reinterpret_cast<float2*>(&ST[row * 4 + half * 2]) = st;
      }
    }
  }
  __syncthreads();   // bar4: ST ready; all VT (V^T) reads retired

  // ---- phase 4a: LayerNorm -> bf16 output staged into VT (XS layout) ----
  {
    float mu[4], rstd[4];
    bool wr[4];
#pragma unroll
    for (int r = 0; r < 4; ++r) {
      int row = mtw * 16 + lhi * 4 + r;
      float4 st = *reinterpret_cast<const float4*>(&ST[row * 4]);
      float ssum = st.x + st.z;
      float ssq  = st.y + st.w;
      float m = ssum * (1.f / 256.f);
      float var = ssq * (1.f / 256.f) - m * m;
      mu[r] = m;
      rstd[r] = rsqrtf(var + 1e-5f);
      wr[r] = row < J_;
    }
#pragma unroll
    for (int i = 0; i < 8; ++i) {
      int c = half * 128 + i * 16 + l15;
      float g = ln_g[c];
      float b = ln_b[c];
#pragma unroll
      for (int r = 0; r < 4; ++r) {
        if (wr[r]) {
          int row = mtw * 16 + lhi * 4 + r;
          VT[row * 256 + (c ^ ((row & 7) << 3))] =
              f2b((y[i][r] - mu[r]) * rstd[r] * g + b);
        }
      }
    }
  }
  __syncthreads();   // bar5: staged output visible

  // ---- phase 4b: lane-contiguous nontemporal f32x4 stores ----
  {
    float* ob = out + (size_t)pos * 6400;
#pragma unroll
    for (int q = 0; q < 7; ++q) {
      int f = q * 256 + tt;                  // float4 index, 1600 total
      if (f < 1600) {
        int row = f >> 6;                    // 0..24
        int c = (f & 63) * 4;
        uint2 pk = *reinterpret_cast<const uint2*>(
            &VT[row * 256 + (c ^ ((row & 7) << 3))]);
        f32x4 o;
        o[0] = b2f((ushort)(pk.x & 0xffff));
        o[1] = b2f((ushort)(pk.x >> 16));
        o[2] = b2f((ushort)(pk.y & 0xffff));
        o[3] = b2f((ushort)(pk.y >> 16));
        __builtin_nontemporal_store(o, reinterpret_cast<f32x4*>(ob + f * 4));
      }
    }
  }
}

// ---------------------------------------------------------------------------
extern "C" void kernel_launch(void* const* d_in, const int* in_sizes, int n_in,
                              void* d_out, int out_size, void* d_ws, size_t ws_size,
                              hipStream_t stream) {
  const float* x        = (const float*)d_in[0];
  const float* bias_mat = (const float*)d_in[1];
  const float* Wq       = (const float*)d_in[2];
  const float* bq       = (const float*)d_in[3];
  const float* Wk       = (const float*)d_in[4];
  const float* bk       = (const float*)d_in[5];
  const float* Wv       = (const float*)d_in[6];
  const float* bv       = (const float*)d_in[7];
  const float* attn_w   = (const float*)d_in[8];
  const float* att_bias = (const float*)d_in[9];
  const float* ln_g     = (const float*)d_in[10];
  const float* ln_b     = (const float*)d_in[11];
  float* out = (float*)d_out;

  ushort* wpack = (ushort*)d_ws;                       // 196608 B
  float*  bm2   = (float*)((char*)d_ws + 196608);      // 4096 B
  float*  awT   = (float*)((char*)d_ws + 200704);      // 6400 B

  prepack_kernel<<<395, 256, 0, stream>>>(Wq, Wk, Wv, bias_mat, att_bias, attn_w,
                                          wpack, bm2, awT);
  fused_attn_kernel<<<NPOS / 2, 512, 0, stream>>>(x, bq, bk, bv, ln_g, ln_b,
                                                  wpack, bm2, awT, out);
}

// Round 21
// 138.701 us; speedup vs baseline: 1.3867x; 1.1357x over previous
//
#include <hip/hip_runtime.h>

#define J_ 25
#define C_ 256
#define H_ 64
#define NPOS 8192
#define LOG2E 1.4426950408889634f
#define KSCALE 0.18033688011112042f   // 0.125 * LOG2E

typedef __attribute__((ext_vector_type(8))) short short8;   // 8 bf16
typedef __attribute__((ext_vector_type(4))) float f32x4;    // MFMA acc

__device__ __forceinline__ ushort f2b(float f) {
  union { float f; unsigned u; } v; v.f = f;
  unsigned r = v.u + 0x7FFFu + ((v.u >> 16) & 1u);  // RNE
  return (ushort)(r >> 16);
}
__device__ __forceinline__ float b2f(ushort u) {
  union { unsigned u; float f; } v; v.u = ((unsigned)u) << 16; return v.f;
}
// HW packed f32x2 -> bf16x2 (RNE), lo = a, hi = b
__device__ __forceinline__ uint cvtpk(float a, float b) {
  uint r;
  asm("v_cvt_pk_bf16_f32 %0, %1, %2" : "=v"(r) : "v"(a), "v"(b));
  return r;
}

// ---------------------------------------------------------------------------
// Prepack: wpack = bf16 B-fragments of [Wq|Wk*KSCALE|Wv] (384 cols, 24 nt).
// bm2[j][a] = (att_bias[a] + bias_mat[j][a]) * LOG2E, -1e30 for a>=25.
// awT[j][h] = attn_w[h][j] * LOG2E.
// ---------------------------------------------------------------------------
__global__ void prepack_kernel(const float* __restrict__ Wq, const float* __restrict__ Wk,
                               const float* __restrict__ Wv, const float* __restrict__ bias_mat,
                               const float* __restrict__ att_bias, const float* __restrict__ attn_w,
                               ushort* __restrict__ wpack, float* __restrict__ bm2,
                               float* __restrict__ awT) {
  int idx = blockIdx.x * 256 + threadIdx.x;
  if (idx < 98304) {
    int e  = idx & 7;
    int l  = (idx >> 3) & 63;
    int ks = (idx >> 9) & 7;
    int nt = idx >> 12;                       // 0..23
    int k = ks * 32 + (l >> 4) * 8 + e;       // 0..255
    int n = nt * 16 + (l & 15);               // 0..383
    float v;
    if (n < H_)            v = Wq[k * H_ + n];
    else if (n < 2 * H_)   v = Wk[k * H_ + (n - H_)] * KSCALE;
    else                   v = Wv[k * C_ + (n - 2 * H_)];
    wpack[idx] = f2b(v);
  } else if (idx < 98304 + 1024) {
    int j2 = idx - 98304;
    int j = j2 >> 5, a = j2 & 31;
    float v;
    if (a < J_) v = (att_bias[a] + ((j < J_) ? bias_mat[j * J_ + a] : 0.f)) * LOG2E;
    else        v = -1e30f;
    bm2[j2] = v;
  } else if (idx < 98304 + 1024 + 1600) {
    int j2 = idx - (98304 + 1024);
    int j = j2 >> 6, h = j2 & 63;             // j<25, h<64
    awT[j2] = attn_w[h * J_ + j] * LOG2E;
  }
}

// ---------------------------------------------------------------------------
// Fused kernel (R17 final): SPATIAL 2-position blocks — 512 threads,
// threads 0-255 do position 2*bid, 256-511 do 2*bid+1 in disjoint 25,088 B
// LDS regions.  Nontemporal final stores keep the 205 MB out stream from
// claiming L2 write-allocate capacity (the −18% lever).  4 barriers.
// ---------------------------------------------------------------------------
__global__ __launch_bounds__(512) void fused_attn_kernel(
    const float* __restrict__ x,
    const float* __restrict__ bq, const float* __restrict__ bk,
    const float* __restrict__ bv,
    const float* __restrict__ ln_g, const float* __restrict__ ln_b,
    const ushort* __restrict__ wpack, const float* __restrict__ bm2,
    const float* __restrict__ awT,
    float* __restrict__ out)
{
  __shared__ __align__(16) char SMEM[2 * 25088];

  const int t   = threadIdx.x;
  const int ph  = t >> 8;                     // position half 0/1
  const int tt  = t & 255;                    // thread within position
  char* BASE = SMEM + ph * 25088;
  ushort* VT = (ushort*)BASE;                 // [256][32] bf16 (phase 3)
  ushort* XS = (ushort*)BASE;                 // [25][256] bf16 (phases 0-1, aliases VT)
  ushort* QS = (ushort*)(BASE + 16384);       // [32][64]  4096 B
  ushort* KS = (ushort*)(BASE + 20480);       // [32][64]  4096 B
  float*  ST = (float*)(BASE + 24576);        // [32][4]   512 B

  const int lane = tt & 63;
  const int w    = tt >> 6;
  const int l15  = lane & 15;
  const int lhi  = lane >> 4;
  const int half = w & 1;
  const int mtw  = w >> 1;
  const int pos  = blockIdx.x * 2 + ph;

  const int hcol = w * 16 + l15;                  // 0..63
  const float* xg = x + (size_t)pos * 6400;
  const ushort* wbase = wpack + w * 4096 + (size_t)lane * 8;

  float biasv[6];
  // ---- phase 0: stage x -> XS bf16 (coalesced) + small prefetches ----
  {
    float4 xf[7];
#pragma unroll
    for (int i = 0; i < 6; ++i)
      xf[i] = *reinterpret_cast<const float4*>(xg + (i * 256 + tt) * 4);
    if (tt < 64) xf[6] = *reinterpret_cast<const float4*>(xg + (1536 + tt) * 4);

    biasv[0] = bq[hcol];
    biasv[1] = bk[hcol] * KSCALE;
    biasv[2] = bv[hcol];
    biasv[3] = bv[64 + hcol];
    biasv[4] = bv[128 + hcol];
    biasv[5] = bv[192 + hcol];

#pragma unroll
    for (int i = 0; i < 7; ++i) {
      if (i < 6 || tt < 64) {
        int f = i * 256 + tt;
        int row = f >> 6;                     // 0..24
        int c = (f & 63) * 4;
        int ci = c ^ ((row & 7) << 3);
        uint2 pk;
        pk.x = cvtpk(xf[i].x, xf[i].y);
        pk.y = cvtpk(xf[i].z, xf[i].w);
        *reinterpret_cast<uint2*>(&XS[row * 256 + ci]) = pk;
      }
    }
  }
  // prefetch ks=0 weight fragments (independent of XS)
  short8 bf0[6];
#pragma unroll
  for (int i = 0; i < 6; ++i)
    bf0[i] = *reinterpret_cast<const short8*>(wbase + i * 16384);
  __syncthreads();   // bar1: XS ready (both halves)

  // ---- phase 1: projections (ks-outer)  [32x256] @ [256x384] ----
  f32x4 acc[2][6];
  uint resb[16];     // packed bf16 residual (row pairs)
  {
#pragma unroll
    for (int m = 0; m < 2; ++m)
#pragma unroll
      for (int i = 0; i < 6; ++i) acc[m][i] = (f32x4){0.f, 0.f, 0.f, 0.f};

    const int row1 = (l15 < 9) ? 16 + l15 : 0;  // clamped pad row (garbage ok)
    __builtin_amdgcn_s_setprio(1);
#pragma unroll
    for (int ks = 0; ks < 8; ++ks) {
      int co = ks * 32 + lhi * 8;
      short8 a0 = *reinterpret_cast<const short8*>(&XS[l15 * 256 + (co ^ ((l15 & 7) << 3))]);
      short8 a1 = *reinterpret_cast<const short8*>(&XS[row1 * 256 + (co ^ ((row1 & 7) << 3))]);
#pragma unroll
      for (int i = 0; i < 6; ++i) {
        short8 bfr;
        if (ks == 0) bfr = bf0[i];
        else         bfr = *reinterpret_cast<const short8*>(wbase + i * 16384 + ks * 512);
        acc[0][i] = __builtin_amdgcn_mfma_f32_16x16x32_bf16(a0, bfr, acc[0][i], 0, 0, 0);
        acc[1][i] = __builtin_amdgcn_mfma_f32_16x16x32_bf16(a1, bfr, acc[1][i], 0, 0, 0);
      }
    }
    __builtin_amdgcn_s_setprio(0);

    // awT fold values (L2-hot; already *LOG2E)
    float awv[8];
#pragma unroll
    for (int m = 0; m < 2; ++m)
#pragma unroll
      for (int r = 0; r < 4; ++r) {
        int row = m * 16 + lhi * 4 + r;
        int ac = row < J_ ? row : J_ - 1;
        awv[m * 4 + r] = awT[ac * 64 + hcol];
      }

    // epilogue A: QS and KS (non-aliased region); cvt_pk pairs + hi-extract
#pragma unroll
    for (int m = 0; m < 2; ++m) {
      float q0 = acc[m][0][0] + biasv[0], q1 = acc[m][0][1] + biasv[0];
      float q2 = acc[m][0][2] + biasv[0], q3 = acc[m][0][3] + biasv[0];
      float k0 = acc[m][1][0] + biasv[1] + awv[m * 4 + 0];
      float k1 = acc[m][1][1] + biasv[1] + awv[m * 4 + 1];
      float k2 = acc[m][1][2] + biasv[1] + awv[m * 4 + 2];
      float k3 = acc[m][1][3] + biasv[1] + awv[m * 4 + 3];
      uint qp0 = cvtpk(q0, q1), qp1 = cvtpk(q2, q3);
      uint kp0 = cvtpk(k0, k1), kp1 = cvtpk(k2, k3);
#pragma unroll
      for (int r = 0; r < 4; ++r) {
        int row = m * 16 + lhi * 4 + r;
        int sw  = (row & 7) << 3;
        uint qp = (r < 2) ? qp0 : qp1;
        uint kp = (r < 2) ? kp0 : kp1;
        ushort qv = (r & 1) ? (ushort)(qp >> 16) : (ushort)(qp & 0xffff);
        ushort kv = (r & 1) ? (ushort)(kp >> 16) : (ushort)(kp & 0xffff);
        QS[row * 64 + (hcol ^ sw)] = qv;
        KS[row * 64 + (hcol ^ sw)] = kv;
      }
    }

    // residual extraction from XS (must finish before bar2; packed bf16)
#pragma unroll
    for (int i = 0; i < 8; ++i) {
      int c = (half * 8 + i) * 16 + l15;
#pragma unroll
      for (int rr = 0; rr < 2; ++rr) {
        int row0 = mtw * 16 + lhi * 4 + 2 * rr;
        int rc0 = row0 < J_ ? row0 : J_ - 1;
        int rc1 = (row0 + 1) < J_ ? row0 + 1 : J_ - 1;
        ushort u0 = XS[rc0 * 256 + (c ^ ((rc0 & 7) << 3))];
        ushort u1 = XS[rc1 * 256 + (c ^ ((rc1 & 7) << 3))];
        resb[i * 2 + rr] = (uint)u0 | ((uint)u1 << 16);
      }
    }
  }
  __syncthreads();   // bar2: all XS reads retired; QS/KS visible

  // epilogue B: V^T into VT (overlays XS) — batched 4-row uint2 writes
  {
#pragma unroll
    for (int i = 2; i < 6; ++i) {
      int c = hcol + (i - 2) * 64;
      int csw = (c & 3) << 3;
#pragma unroll
      for (int m = 0; m < 2; ++m) {
        int row0 = m * 16 + lhi * 4;
        uint2 pk;
        pk.x = cvtpk(acc[m][i][0] + biasv[i], acc[m][i][1] + biasv[i]);
        pk.y = cvtpk(acc[m][i][2] + biasv[i], acc[m][i][3] + biasv[i]);
        *reinterpret_cast<uint2*>(&VT[c * 32 + (row0 ^ csw)]) = pk;
      }
    }
  }
  __syncthreads();   // bar3: VT visible; softmax+PV run barrier-free

  // ---- phase 2: scores (transposed) + wave-parallel softmax + shuffle-P ----
  short8 pa;
  {
    const int jrow = mtw * 16 + l15;
    const int jsw  = (jrow & 7) << 3;
    short8 qf0 = *reinterpret_cast<const short8*>(&QS[jrow * 64 + ((lhi * 8) ^ jsw)]);
    short8 qf1 = *reinterpret_cast<const short8*>(&QS[jrow * 64 + ((32 + lhi * 8) ^ jsw)]);

    const int a0r = l15, a1r = 16 + l15;
    const int s0w = (a0r & 7) << 3, s1w = (a1r & 7) << 3;
    short8 m00 = *reinterpret_cast<const short8*>(&KS[a0r * 64 + ((lhi * 8) ^ s0w)]);
    short8 m01 = *reinterpret_cast<const short8*>(&KS[a0r * 64 + ((32 + lhi * 8) ^ s0w)]);
    short8 m10 = *reinterpret_cast<const short8*>(&KS[a1r * 64 + ((lhi * 8) ^ s1w)]);
    short8 m11 = *reinterpret_cast<const short8*>(&KS[a1r * 64 + ((32 + lhi * 8) ^ s1w)]);

    f32x4 s0 = {0.f, 0.f, 0.f, 0.f}, s1 = {0.f, 0.f, 0.f, 0.f};
    __builtin_amdgcn_s_setprio(1);
    s0 = __builtin_amdgcn_mfma_f32_16x16x32_bf16(m00, qf0, s0, 0, 0, 0);
    s0 = __builtin_amdgcn_mfma_f32_16x16x32_bf16(m01, qf1, s0, 0, 0, 0);
    s1 = __builtin_amdgcn_mfma_f32_16x16x32_bf16(m10, qf0, s1, 0, 0, 0);
    s1 = __builtin_amdgcn_mfma_f32_16x16x32_bf16(m11, qf1, s1, 0, 0, 0);
    __builtin_amdgcn_s_setprio(0);

    float4 bm0 = *reinterpret_cast<const float4*>(&bm2[jrow * 32 + lhi * 4]);
    float4 bm1 = *reinterpret_cast<const float4*>(&bm2[jrow * 32 + 16 + lhi * 4]);
    float v0[4], v1[4];
    v0[0] = s0[0] + bm0.x; v0[1] = s0[1] + bm0.y; v0[2] = s0[2] + bm0.z; v0[3] = s0[3] + bm0.w;
    v1[0] = s1[0] + bm1.x; v1[1] = s1[1] + bm1.y; v1[2] = s1[2] + bm1.z; v1[3] = s1[3] + bm1.w;

    float mx = fmaxf(fmaxf(fmaxf(v0[0], v0[1]), fmaxf(v0[2], v0[3])),
                     fmaxf(fmaxf(v1[0], v1[1]), fmaxf(v1[2], v1[3])));
    mx = fmaxf(mx, __shfl_xor(mx, 16));
    mx = fmaxf(mx, __shfl_xor(mx, 32));

    float e0[4], e1[4], sum = 0.f;
#pragma unroll
    for (int r = 0; r < 4; ++r) { e0[r] = __builtin_exp2f(v0[r] - mx); sum += e0[r]; }
#pragma unroll
    for (int r = 0; r < 4; ++r) { e1[r] = __builtin_exp2f(v1[r] - mx); sum += e1[r]; }
    sum += __shfl_xor(sum, 16);
    sum += __shfl_xor(sum, 32);
    float inv = 1.0f / sum;

    uint w0 = cvtpk(e0[0] * inv, e0[1] * inv);
    uint w1 = cvtpk(e0[2] * inv, e0[3] * inv);
    uint w2 = cvtpk(e1[0] * inv, e1[1] * inv);
    uint w3 = cvtpk(e1[2] * inv, e1[3] * inv);

    // consumer lane (l15,lhi) wants P[jrow][k = lhi*8 .. lhi*8+7]
    int srcA = l15 + (((lhi * 2) & 3) << 4);
    int srcB = srcA + 16;
    uint a0s = (uint)__shfl((int)w0, srcA);
    uint a1s = (uint)__shfl((int)w1, srcA);
    uint a2s = (uint)__shfl((int)w0, srcB);
    uint a3s = (uint)__shfl((int)w1, srcB);
    uint b0s = (uint)__shfl((int)w2, srcA);
    uint b1s = (uint)__shfl((int)w3, srcA);
    uint b2s = (uint)__shfl((int)w2, srcB);
    uint b3s = (uint)__shfl((int)w3, srcB);
    bool sel = lhi >= 2;
    union { uint u[4]; short8 s; } pau;
    pau.u[0] = sel ? b0s : a0s;
    pau.u[1] = sel ? b1s : a1s;
    pau.u[2] = sel ? b2s : a2s;
    pau.u[3] = sel ? b3s : a3s;
    pa = pau.s;
  }

  // ---- phase 3: PV + packed-register residual + LN stats ----
  float y[8][4];
  {
    float s1a[4] = {0.f, 0.f, 0.f, 0.f}, s2a[4] = {0.f, 0.f, 0.f, 0.f};
    __builtin_amdgcn_s_setprio(1);
#pragma unroll
    for (int i = 0; i < 8; ++i) {
      int c = (half * 8 + i) * 16 + l15;
      short8 vb = *reinterpret_cast<const short8*>(
          &VT[c * 32 + ((lhi * 8) ^ ((c & 3) << 3))]);
      f32x4 z = {0.f, 0.f, 0.f, 0.f};
      f32x4 av = __builtin_amdgcn_mfma_f32_16x16x32_bf16(pa, vb, z, 0, 0, 0);
#pragma unroll
      for (int r = 0; r < 4; ++r) {
        uint pr = resb[i * 2 + (r >> 1)];
        ushort ub = (r & 1) ? (ushort)(pr >> 16) : (ushort)(pr & 0xffff);
        float yy = av[r] + b2f(ub);
        y[i][r] = yy;
        s1a[r] += yy;
        s2a[r] += yy * yy;
      }
    }
    __builtin_amdgcn_s_setprio(0);
#pragma unroll
    for (int d = 1; d < 16; d <<= 1) {
#pragma unroll
      for (int r = 0; r < 4; ++r) {
        s1a[r] += __shfl_xor(s1a[r], d);
        s2a[r] += __shfl_xor(s2a[r], d);
      }
    }
    if (l15 == 0) {
#pragma unroll
      for (int r = 0; r < 4; ++r) {
        int row = mtw * 16 + lhi * 4 + r;
        float2 st; st.x = s1a[r]; st.y = s2a[r];
        *reinterpret_cast<float2*>(&ST[row * 4 + half * 2]) = st;
      }
    }
  }
  __syncthreads();   // bar4: ST ready

  // ---- phase 4: LayerNorm + nontemporal store ----
  {
    float* ob = out + (size_t)pos * 6400;
    float mu[4], rstd[4];
    bool wr[4];
#pragma unroll
    for (int r = 0; r < 4; ++r) {
      int row = mtw * 16 + lhi * 4 + r;
      float4 st = *reinterpret_cast<const float4*>(&ST[row * 4]);
      float ssum = st.x + st.z;
      float ssq  = st.y + st.w;
      float m = ssum * (1.f / 256.f);
      float var = ssq * (1.f / 256.f) - m * m;
      mu[r] = m;
      rstd[r] = rsqrtf(var + 1e-5f);
      wr[r] = row < J_;
    }
#pragma unroll
    for (int i = 0; i < 8; ++i) {
      int c = half * 128 + i * 16 + l15;
      float g = ln_g[c];
      float b = ln_b[c];
#pragma unroll
      for (int r = 0; r < 4; ++r) {
        if (wr[r]) {
          int row = mtw * 16 + lhi * 4 + r;
          __builtin_nontemporal_store((y[i][r] - mu[r]) * rstd[r] * g + b,
                                      &ob[row * 256 + c]);
        }
      }
    }
  }
}

// ---------------------------------------------------------------------------
extern "C" void kernel_launch(void* const* d_in, const int* in_sizes, int n_in,
                              void* d_out, int out_size, void* d_ws, size_t ws_size,
                              hipStream_t stream) {
  const float* x        = (const float*)d_in[0];
  const float* bias_mat = (const float*)d_in[1];
  const float* Wq       = (const float*)d_in[2];
  const float* bq       = (const float*)d_in[3];
  const float* Wk       = (const float*)d_in[4];
  const float* bk       = (const float*)d_in[5];
  const float* Wv       = (const float*)d_in[6];
  const float* bv       = (const float*)d_in[7];
  const float* attn_w   = (const float*)d_in[8];
  const float* att_bias = (const float*)d_in[9];
  const float* ln_g     = (const float*)d_in[10];
  const float* ln_b     = (const float*)d_in[11];
  float* out = (float*)d_out;

  ushort* wpack = (ushort*)d_ws;                       // 196608 B
  float*  bm2   = (float*)((char*)d_ws + 196608);      // 4096 B
  float*  awT   = (float*)((char*)d_ws + 200704);      // 6400 B

  prepack_kernel<<<395, 256, 0, stream>>>(Wq, Wk, Wv, bias_mat, att_bias, attn_w,
                                          wpack, bm2, awT);
  fused_attn_kernel<<<NPOS / 2, 512, 0, stream>>>(x, bq, bk, bv, ln_g, ln_b,
                                                  wpack, bm2, awT, out);
}